// Round 21
// baseline (700.798 us; speedup 1.0000x reference)
//
#include <hip/hip_runtime.h>
#include <hip/hip_bf16.h>
#include <math.h>

// Triangle multiplication (outgoing). N=768, C=128.
// Pipeline (v20):
//   k_convw: f32->bf16 weight conversion (lp,lg,rp,rg,gl,op)
//   k_proj : LN(act) + 4 pair projections -> left_t/right_t (plane-major bf16) + act_ln
//            dump (pos-major bf16). GATE MOVED TO K_POST: removes 64/320 MFMAs, the
//            cross-wave gate transpose, and 4 barriers; act_ln dump reuses the proven
//            gate-dump pattern (pure sx unswizzle, 256B rows).
//   k_tri  : per-channel 768^3 NT GEMM -> f32 out (v12 LDS swizzle + v13 plane skew).
//   k_post : v14 two-pass + INLINE GATE: second MFMA stream gacc = mfma(af2, Wg) with af2
//            loaded from act_ln (same proven fragment convention as the op projection);
//            out = (acc+bo) * sigm(gacc+glb). Gate no longer rounded to bf16.
// Falsified (for the record): k_proj barriers/conflicts/write-contig/occupancy/fence-removal;
// k_post swapped-mfma. Fences kept in pair passes (v18: removal -> HBM RMW, WRITE 2.4x).
// Workspace: 1MB weights + 4 * (151MB+32KB) buffers ~= 605.2MB.

#define NRES 768
#define CD 128
#define NN (768 * 768)
#define PS2 (NN + 128)   // u16 elements per bf16 channel plane (+256B skew)
#define PS4 (NN + 64)    // f32 elements per f32 channel plane (+256B skew)

typedef unsigned short u16;
typedef unsigned int u32;
typedef __attribute__((ext_vector_type(8))) short bf16x8;
typedef __attribute__((ext_vector_type(4))) float f32x4;

__device__ __forceinline__ float b2f(u16 u) {
  union { u32 i; float f; } v; v.i = ((u32)u) << 16; return v.f;
}
__device__ __forceinline__ u16 f2bf(float f) {
  __hip_bfloat16 h = __float2bfloat16(f);
  return *reinterpret_cast<u16*>(&h);
}
__device__ __forceinline__ float sigm(float x) {
  return __builtin_amdgcn_rcpf(1.0f + __builtin_amdgcn_exp2f(x * -1.44269504f));
}

__device__ __forceinline__ void async16(u16* lds, const u16* g) {
  __builtin_amdgcn_global_load_lds((const __attribute__((address_space(1))) void*)g,
                                   (__attribute__((address_space(3))) void*)lds, 16, 0, 0);
}

// In-wave LDS fence: drains this wave's LDS ops AND batches the following dump stream
// (v18 showed removing it causes HBM RMW via interleaved partial-line writes).
__device__ __forceinline__ void lds_fence() {
  asm volatile("s_waitcnt lgkmcnt(0)" ::: "memory");
  __builtin_amdgcn_sched_barrier(0);
}

// ---------------- K0: weight conversion ----------------
__global__ void k_convw(const float* __restrict__ a, const float* __restrict__ b,
                        const float* __restrict__ c, const float* __restrict__ d,
                        const float* __restrict__ e, const float* __restrict__ f,
                        u16* __restrict__ wb) {
  int i = blockIdx.x * 256 + threadIdx.x;
  int m = i >> 14, r = i & 16383;
  const float* s = (m == 0) ? a : (m == 1) ? b : (m == 2) ? c : (m == 3) ? d : (m == 4) ? e : f;
  wb[i] = f2bf(s[r]);
}

// ---------------- K1: LN + 4 projections + act_ln dump (128-row tile) ----------------
__global__ __launch_bounds__(256, 3) void k_proj(
    const float* __restrict__ act, const float* __restrict__ mask,
    const float* __restrict__ lnw, const float* __restrict__ lnb,
    const u16* __restrict__ wb,
    const float* __restrict__ lpb, const float* __restrict__ lgb,
    const float* __restrict__ rpb, const float* __restrict__ rgb,
    u16* __restrict__ left_t, u16* __restrict__ right_t, u16* __restrict__ actln) {
  __shared__ u16 sx[128][128];   // act_ln, XOR-swizzled (key=(row&7)<<3 in u16 units)
  __shared__ u16 stb[128 * 74];  // pair staging: [128 d][stride 74] wave-private
  __shared__ float fmask[128];
  const int t = threadIdx.x;
  const int pos0 = blockIdx.x * 128;
  const int l = t & 63, w = t >> 6;
  const int lr = l & 15, g4 = l >> 4;

  // ---- phase 1: LayerNorm, 2 threads per row (64 ch each)
  {
    const int r = t >> 1, q = t & 1;
    const float* arow = act + (size_t)(pos0 + r) * CD + q * 64;
    float4 xv[16];
    float s = 0.f, ss = 0.f;
#pragma unroll
    for (int j = 0; j < 16; ++j) {
      xv[j] = *(const float4*)(arow + j * 4);
      s += xv[j].x + xv[j].y + xv[j].z + xv[j].w;
      ss += xv[j].x * xv[j].x + xv[j].y * xv[j].y + xv[j].z * xv[j].z + xv[j].w * xv[j].w;
    }
    s += __shfl_xor(s, 1); ss += __shfl_xor(ss, 1);
    float mu = s * (1.0f / CD);
    float rs = rsqrtf(ss * (1.0f / CD) - mu * mu + 1e-5f);
    const int key = (r & 7) << 3;
#pragma unroll
    for (int j = 0; j < 16; j += 2) {
      u16 o[8] __attribute__((aligned(16)));
      const float* xx = (const float*)&xv[j];
      int c0 = q * 64 + j * 4;
#pragma unroll
      for (int e2 = 0; e2 < 8; ++e2)
        o[e2] = f2bf((xx[e2] - mu) * rs * lnw[c0 + e2] + lnb[c0 + e2]);
      *(bf16x8*)&sx[r][c0 ^ key] = *(const bf16x8*)o;
    }
    if (t < 128) fmask[t] = mask[pos0 + t];
  }
  __syncthreads();

  // ---- act_ln dump: pos-major 256B rows (proven gate-dump pattern, sx unswizzle).
  // Issued before the pair passes so the stores drain under the MFMA work.
#pragma unroll
  for (int it = 0; it < 2; ++it) {
    const int row = it * 64 + (t >> 2);
    const int key = (row & 7) << 3;
    const int dc = (t & 3) * 32;
#pragma unroll
    for (int jj = 0; jj < 4; ++jj) {
      const int c0 = dc + jj * 8;
      *(bf16x8*)&actln[(size_t)(pos0 + row) * CD + c0] = *(const bf16x8*)&sx[row][c0 ^ key];
    }
  }

  // ---- pair projection: wave w owns d in [w*32, w*32+32); WAVE-LOCAL staging + dumps
  auto pair_pass = [&](const u16* __restrict__ WP, const u16* __restrict__ WG,
                       const float* __restrict__ bP, const float* __restrict__ bG,
                       u16* __restrict__ dst) {
    bf16x8 bp[2][4], bg[2][4];
    float biasP[2], biasG[2];
    int dd[2];
#pragma unroll
    for (int c2 = 0; c2 < 2; ++c2) {
      dd[c2] = w * 32 + c2 * 16 + lr;
#pragma unroll
      for (int kk = 0; kk < 4; ++kk) {
        bp[c2][kk] = *(const bf16x8*)&WP[dd[c2] * CD + kk * 32 + g4 * 8];
        bg[c2][kk] = *(const bf16x8*)&WG[dd[c2] * CD + kk * 32 + g4 * 8];
      }
      biasP[c2] = bP[dd[c2]];
      biasG[c2] = bG[dd[c2]];
    }
#pragma unroll
    for (int mc = 0; mc < 2; ++mc) {
      lds_fence();   // prior dump-reads retired before this wave overwrites its stb region
#pragma unroll
      for (int m = 0; m < 4; ++m) {
        const int row = mc * 64 + m * 16 + lr;
        const int key = (row & 7) << 3;
        bf16x8 af[4];
#pragma unroll
        for (int kk = 0; kk < 4; ++kk)
          af[kk] = *(const bf16x8*)&sx[row][(kk * 32 + g4 * 8) ^ key];
        const int rowc = m * 16 + g4 * 4;
        float fm[4];
#pragma unroll
        for (int r = 0; r < 4; ++r) fm[r] = fmask[mc * 64 + rowc + r];
#pragma unroll
        for (int c2 = 0; c2 < 2; ++c2) {
          f32x4 aP = {0.f, 0.f, 0.f, 0.f}, aG = {0.f, 0.f, 0.f, 0.f};
#pragma unroll
          for (int kk = 0; kk < 4; ++kk) {
            aP = __builtin_amdgcn_mfma_f32_16x16x32_bf16(af[kk], bp[c2][kk], aP, 0, 0, 0);
            aG = __builtin_amdgcn_mfma_f32_16x16x32_bf16(af[kk], bg[c2][kk], aG, 0, 0, 0);
          }
          u16 o[4] __attribute__((aligned(8)));
#pragma unroll
          for (int r = 0; r < 4; ++r)
            o[r] = f2bf((aP[r] + biasP[c2]) * sigm(aG[r] + biasG[c2]) * fm[r]);
          *(uint2*)&stb[dd[c2] * 74 + rowc] = *(const uint2*)o;
        }
      }
      lds_fence();   // stage-writes complete before this wave's dump-reads
      // wave-local dump: this wave's 32 d x 64 pos; 8 d/instr x 128B contiguous each
#pragma unroll
      for (int it = 0; it < 4; ++it) {
        const int d = w * 32 + it * 8 + (l >> 3), off = (l & 7) * 8;
        *(bf16x8*)&dst[(size_t)d * PS2 + pos0 + mc * 64 + off] = *(const bf16x8*)&stb[d * 74 + off];
      }
    }
  };

  pair_pass(wb, wb + 16384, lpb, lgb, left_t);
  pair_pass(wb + 2 * 16384, wb + 3 * 16384, rpb, rgb, right_t);
}

// ---------------- K2: per-channel triangle GEMM, f32 output, split launch ----------------
__global__ __launch_bounds__(256, 4) void k_tri(
    const u16* __restrict__ left_t, const u16* __restrict__ right_t,
    float* __restrict__ o1, float* __restrict__ o2, float* __restrict__ o3,
    int cbase) {
  __shared__ u16 sA[2][128 * 32];
  __shared__ u16 sB[2][128 * 32];
  const int t = threadIdx.x, l = t & 63, w = t >> 6;
  const int bid = blockIdx.x;                 // 2304 blocks: 64 ch x 36 tiles
  const int xcd = bid & 7, idx = bid >> 3;    // idx in [0,288)
  const int c = cbase + xcd * 8 + idx / 36;
  const int tile = idx - (idx / 36) * 36;
  const int ti = tile / 6, tj = tile - (tile / 6) * 6;
  const u16* A = left_t + (size_t)c * PS2 + (size_t)ti * 128 * NRES;
  const u16* B = right_t + (size_t)c * PS2 + (size_t)tj * 128 * NRES;
  const int lr = l & 15, cj = l >> 4;
  const int wr = (w >> 1) * 64, wc = (w & 1) * 64;
  const int wbase = t & ~63;
  f32x4 acc[4][4];
#pragma unroll
  for (int m = 0; m < 4; ++m)
#pragma unroll
    for (int n = 0; n < 4; ++n) acc[m][n] = (f32x4){0.f, 0.f, 0.f, 0.f};

  // v12 swizzle: LDS slot ch of row holds GLOBAL chunk ch^((row>>1)&3); read slot
  // cj^((row>>1)&3) -> global chunk cj. 8-way bank conflict -> 2-way (free).
  auto stage = [&](int p, int k0) {
#pragma unroll
    for (int it = 0; it < 2; ++it) {
      int li = it * 256 + t;
      int row = li >> 2, ch = li & 3;
      int cs = ch ^ ((row >> 1) & 3);
      async16(&sA[p][(it * 256 + wbase) * 8], A + (size_t)row * NRES + k0 + cs * 8);
      async16(&sB[p][(it * 256 + wbase) * 8], B + (size_t)row * NRES + k0 + cs * 8);
    }
  };

  stage(0, 0);
  __syncthreads();
  for (int ks = 0; ks < 24; ++ks) {
    const int p = ks & 1;
    if (ks < 23) stage(p ^ 1, (ks + 1) * 32);   // prefetch issued BEFORE compute
    bf16x8 av[4], bv[4];
#pragma unroll
    for (int m = 0; m < 4; ++m) {
      const int row = wr + m * 16 + lr;
      av[m] = *(const bf16x8*)&sA[p][row * 32 + ((cj ^ ((row >> 1) & 3)) * 8)];
    }
#pragma unroll
    for (int n = 0; n < 4; ++n) {
      const int row = wc + n * 16 + lr;
      bv[n] = *(const bf16x8*)&sB[p][row * 32 + ((cj ^ ((row >> 1) & 3)) * 8)];
    }
#pragma unroll
    for (int m = 0; m < 4; ++m)
#pragma unroll
      for (int n = 0; n < 4; ++n)
        acc[m][n] = __builtin_amdgcn_mfma_f32_16x16x32_bf16(av[m], bv[n], acc[m][n], 0, 0, 0);
    __syncthreads();   // drains prefetch vmcnt; next iter reads buf p^1
  }

  // f32 output region select (ch 0-63 -> o1; 64-95 -> o2; 96-127 -> o3), skewed planes
  float* O = (c < 64) ? (o1 + (size_t)c * PS4)
           : (c < 96) ? (o2 + (size_t)(c - 64) * PS4)
                      : (o3 + (size_t)(c - 96) * PS4);
  const int r0l = (l >> 4) << 2;
#pragma unroll
  for (int m = 0; m < 4; ++m) {
#pragma unroll
    for (int n = 0; n < 4; ++n) {
      int row = ti * 128 + wr + m * 16 + r0l;
      int col = tj * 128 + wc + n * 16 + lr;
#pragma unroll
      for (int r = 0; r < 4; ++r)
        O[(size_t)(row + r) * NRES + col] = acc[m][n][r];   // 16 lanes x 4B = aligned 64B lines
    }
  }
}

// ---------------- K3: f32 LN + op-linear + INLINE GATE (256-pos tiles, two-pass) ----------------
__global__ __launch_bounds__(256, 2) void k_post(
    const float* __restrict__ o1, const float* __restrict__ o2, const float* __restrict__ o3,
    const u16* __restrict__ actln,
    const float* __restrict__ clnw, const float* __restrict__ clnb,
    const u16* __restrict__ wop, const u16* __restrict__ wgl,
    const float* __restrict__ opb, const float* __restrict__ glb,
    float* __restrict__ out) {
  __shared__ u16 sx[256][128];       // normalized bf16, XOR key (pos&7)<<3 — 64KB
  __shared__ float ps[4][256];       // per-wave partial sums
  __shared__ float pss[4][256];      // per-wave partial sumsq
  __shared__ float mu_s[256], rs_s[256];
  const int t = threadIdx.x;
  const int pos0 = blockIdx.x * 256;
  const int l = t & 63, w = t >> 6;

  // ---- A1: stats. Wave w owns planes [w*32, w*32+32) (region-uniform per wave).
  {
    const float* wbase = (w < 2) ? (o1 + (size_t)(w * 32) * PS4)
                       : (w == 2) ? o2 : o3;
    float s[4] = {0.f, 0.f, 0.f, 0.f}, ss[4] = {0.f, 0.f, 0.f, 0.f};
#pragma unroll
    for (int pp = 0; pp < 32; ++pp) {
      const float4 v = *(const float4*)&wbase[(size_t)pp * PS4 + pos0 + l * 4];
      s[0] += v.x; ss[0] += v.x * v.x;
      s[1] += v.y; ss[1] += v.y * v.y;
      s[2] += v.z; ss[2] += v.z * v.z;
      s[3] += v.w; ss[3] += v.w * v.w;
    }
#pragma unroll
    for (int e = 0; e < 4; ++e) {
      ps[w][l * 4 + e] = s[e];
      pss[w][l * 4 + e] = ss[e];
    }
  }
  __syncthreads();
  {
    const float s4 = ps[0][t] + ps[1][t] + ps[2][t] + ps[3][t];
    const float ss4 = pss[0][t] + pss[1][t] + pss[2][t] + pss[3][t];
    const float mu = s4 * (1.0f / CD);
    mu_s[t] = mu;
    rs_s[t] = rsqrtf(ss4 * (1.0f / CD) - mu * mu + 1e-5f);
  }
  __syncthreads();

  // ---- A2: re-read (L2-hot), LN once f32->bf16 into sx.
  {
    const int q = t & 15, g = t >> 4;
    const int ch0 = q * 8;
    const float* base = (ch0 < 64) ? (o1 + (size_t)ch0 * PS4)
                      : (ch0 < 96) ? (o2 + (size_t)(ch0 - 64) * PS4)
                                   : (o3 + (size_t)(ch0 - 96) * PS4);
    float4 wv[2], bv[2];
#pragma unroll
    for (int j = 0; j < 2; ++j) {
      wv[j] = *(const float4*)&clnw[ch0 + j * 4];
      bv[j] = *(const float4*)&clnb[ch0 + j * 4];
    }
#pragma unroll
    for (int mc = 0; mc < 4; ++mc) {
      const int p0 = mc * 64 + g * 4;
      float4 x[8];
#pragma unroll
      for (int cc = 0; cc < 8; ++cc)
        x[cc] = *(const float4*)&base[(size_t)cc * PS4 + pos0 + p0];
#pragma unroll
      for (int e = 0; e < 4; ++e) {
        const int p = p0 + e;
        const float mu = mu_s[p], rs = rs_s[p];
        const int key = (p & 7) << 3;
        u16 o8[8] __attribute__((aligned(16)));
#pragma unroll
        for (int i = 0; i < 8; ++i) {
          const float xv = (e == 0) ? x[i].x : (e == 1) ? x[i].y : (e == 2) ? x[i].z : x[i].w;
          const float wvv = ((const float*)&wv[i >> 2])[i & 3];
          const float bvv = ((const float*)&bv[i >> 2])[i & 3];
          o8[i] = f2bf((xv - mu) * rs * wvv + bvv);
        }
        *(bf16x8*)&sx[p][ch0 ^ key] = *(const bf16x8*)o8;
      }
    }
  }
  __syncthreads();

  // ---- C: wave w owns rows [w*64, w*64+64); four 16-row m-tiles.
  // TWO MFMA streams in the SAME proven convention (acc[r] <-> row prow+r, col d):
  //   acc  = af  (normalized tri-out rows) x wop  -> op projection
  //   gacc = af2 (act_ln rows, from global) x wgl -> gate logits
  const int lr = l & 15, lk8 = (l >> 4) * 8;
  bf16x8 af[4][4], af2[4][4];
#pragma unroll
  for (int m = 0; m < 4; ++m) {
    const int pr = w * 64 + m * 16 + lr;
    const int key = (pr & 7) << 3;
#pragma unroll
    for (int kk = 0; kk < 4; ++kk) {
      af[m][kk] = *(const bf16x8*)&sx[pr][(kk * 32 + lk8) ^ key];
      af2[m][kk] = *(const bf16x8*)&actln[(size_t)(pos0 + pr) * CD + kk * 32 + lk8];
    }
  }
  const int r0l = (l >> 4) << 2;
#pragma unroll
  for (int ct = 0; ct < 8; ++ct) {
    const int d = ct * 16 + lr;
    bf16x8 bv[4], bgl[4];
#pragma unroll
    for (int kk = 0; kk < 4; ++kk) {
      bv[kk] = *(const bf16x8*)&wop[d * CD + kk * 32 + lk8];
      bgl[kk] = *(const bf16x8*)&wgl[d * CD + kk * 32 + lk8];
    }
    const float bo = opb[d];
    const float bgb = glb[d];
#pragma unroll
    for (int m = 0; m < 4; ++m) {
      f32x4 acc = {0.f, 0.f, 0.f, 0.f}, gacc = {0.f, 0.f, 0.f, 0.f};
#pragma unroll
      for (int kk = 0; kk < 4; ++kk) {
        acc = __builtin_amdgcn_mfma_f32_16x16x32_bf16(af[m][kk], bv[kk], acc, 0, 0, 0);
        gacc = __builtin_amdgcn_mfma_f32_16x16x32_bf16(af2[m][kk], bgl[kk], gacc, 0, 0, 0);
      }
      const int prow = w * 64 + m * 16 + r0l;
#pragma unroll
      for (int r = 0; r < 4; ++r) {
        size_t pp = (size_t)(pos0 + prow + r) * CD + d;
        out[pp] = (acc[r] + bo) * sigm(gacc[r] + bgb);
      }
    }
  }
}

extern "C" void kernel_launch(void* const* d_in, const int* in_sizes, int n_in,
                              void* d_out, int out_size, void* d_ws, size_t ws_size,
                              hipStream_t stream) {
  (void)in_sizes; (void)n_in; (void)out_size; (void)ws_size;
  const float* act  = (const float*)d_in[0];
  const float* mask = (const float*)d_in[1];
  const float* lnw  = (const float*)d_in[2];
  const float* lnb  = (const float*)d_in[3];
  const float* lpw  = (const float*)d_in[4];
  const float* lpb  = (const float*)d_in[5];
  const float* rpw  = (const float*)d_in[6];
  const float* rpb  = (const float*)d_in[7];
  const float* lgw  = (const float*)d_in[8];
  const float* lgb  = (const float*)d_in[9];
  const float* rgw  = (const float*)d_in[10];
  const float* rgb  = (const float*)d_in[11];
  const float* clnw = (const float*)d_in[12];
  const float* clnb = (const float*)d_in[13];
  const float* opw  = (const float*)d_in[14];
  const float* opb  = (const float*)d_in[15];
  const float* glw  = (const float*)d_in[16];
  const float* glb  = (const float*)d_in[17];

  char* wsb = (char*)d_ws;
  u16* wb = (u16*)wsb;                            // 6 * 16384 * 2B = 196KB
  const size_t RS = (size_t)128 * PS2 * 2;        // skewed region: 151MB + 32KB
  size_t off = (size_t)1 << 20;
  u16* left_t  = (u16*)(wsb + off); off += RS;
  u16* right_t = (u16*)(wsb + off); off += RS;
  u16* actln   = (u16*)(wsb + off); off += RS;    // pos-major act_ln (replaces gate buffer)
  float* o1    = (float*)(wsb + off); off += RS;  // f32 ch 0-63: 64*PS4*4 <= RS
  float* o2    = (float*)left_t;                  // f32 ch 64-95 over left_t planes 0-63 (dead)
  float* o3    = (float*)right_t;                 // f32 ch 96-127 over right_t planes 0-63 (dead)

  k_convw<<<384, 256, 0, stream>>>(lpw, lgw, rpw, rgw, glw, opw, wb);
  k_proj<<<NN / 128, 256, 0, stream>>>(act, mask, lnw, lnb, wb,
                                       lpb, lgb, rpb, rgb,
                                       left_t, right_t, actln);
  // launch A: channels 0-63 (reads left/right planes 0-63, writes o1 only)
  k_tri<<<2304, 256, 0, stream>>>(left_t, right_t, o1, o2, o3, 0);
  // launch B: channels 64-127 (reads planes 64-127; writes planes 0-63 regions — dead after A)
  k_tri<<<2304, 256, 0, stream>>>(left_t, right_t, o1, o2, o3, 64);
  k_post<<<NN / 256, 256, 0, stream>>>(o1, o2, o3, actln, clnw, clnb,
                                       wb + 5 * 16384, wb + 4 * 16384,
                                       opb, glb, (float*)d_out);
}

// Round 22
// 683.952 us; speedup vs baseline: 1.0246x; 1.0246x over previous
//
#include <hip/hip_runtime.h>
#include <hip/hip_bf16.h>
#include <math.h>

// Triangle multiplication (outgoing). N=768, C=128.  FINAL BUILD (round-15/19, 684us).
// Pipeline:
//   k_convw: f32->bf16 weight conversion (lp,lg,rp,rg,gl,op)
//   k_proj : LN(act) + 5 projections -> left_t/right_t (plane-major bf16), gate (pos-major)
//            wave-local staging+dump with lgkmcnt+sched_barrier fences. The fences also
//            temporally batch each wave's dump stream -> L2 write-combining (v18: removing
//            them ballooned WRITE 442MB->1.06GB via HBM RMW).
//   k_tri  : per-channel 768^3 NT GEMM -> f32 out. v12 source-chunk LDS swizzle (8-way ->
//            2-way) + v13 256B plane skew. Split launch for o2/o3 aliasing.
//   k_post : v14 two-pass: A1 page-friendly 1KB single-plane stats reads, A2 L2-hot re-read
//            + LN -> sx, C MFMA op-projection + gate (fixed k_post 290->180us).
// Falsified experiments (documented): k_proj barriers(v15-neutral)/write-contig(v16)/
// 8-wave(v17-spill)/fence-removal(v18-RMW)/gate-move(v20: k_post af2 scatter reads +76us);
// k_post swapped-mfma (v10/v11 wrong results). f32 tri-output (v7) and two-pass k_post (v14)
// and plane skew (v13) are the attributed wins.
// Workspace: 1MB weights + 4 * (151MB+32KB) buffers ~= 605.2MB.

#define NRES 768
#define CD 128
#define NN (768 * 768)
#define PS2 (NN + 128)   // u16 elements per bf16 channel plane (+256B skew)
#define PS4 (NN + 64)    // f32 elements per f32 channel plane (+256B skew)

typedef unsigned short u16;
typedef unsigned int u32;
typedef __attribute__((ext_vector_type(8))) short bf16x8;
typedef __attribute__((ext_vector_type(4))) float f32x4;

__device__ __forceinline__ float b2f(u16 u) {
  union { u32 i; float f; } v; v.i = ((u32)u) << 16; return v.f;
}
__device__ __forceinline__ u16 f2bf(float f) {
  __hip_bfloat16 h = __float2bfloat16(f);
  return *reinterpret_cast<u16*>(&h);
}
__device__ __forceinline__ float sigm(float x) {
  return __builtin_amdgcn_rcpf(1.0f + __builtin_amdgcn_exp2f(x * -1.44269504f));
}

__device__ __forceinline__ void async16(u16* lds, const u16* g) {
  __builtin_amdgcn_global_load_lds((const __attribute__((address_space(1))) void*)g,
                                   (__attribute__((address_space(3))) void*)lds, 16, 0, 0);
}

// In-wave LDS fence: drains this wave's LDS ops AND batches the following dump stream
// (v18 showed removing it causes HBM RMW via interleaved partial-line writes).
__device__ __forceinline__ void lds_fence() {
  asm volatile("s_waitcnt lgkmcnt(0)" ::: "memory");
  __builtin_amdgcn_sched_barrier(0);
}

// ---------------- K0: weight conversion ----------------
__global__ void k_convw(const float* __restrict__ a, const float* __restrict__ b,
                        const float* __restrict__ c, const float* __restrict__ d,
                        const float* __restrict__ e, const float* __restrict__ f,
                        u16* __restrict__ wb) {
  int i = blockIdx.x * 256 + threadIdx.x;
  int m = i >> 14, r = i & 16383;
  const float* s = (m == 0) ? a : (m == 1) ? b : (m == 2) ? c : (m == 3) ? d : (m == 4) ? e : f;
  wb[i] = f2bf(s[r]);
}

// ---------------- K1: LN + 5 projections (128-row tile, wave-local pair dumps) ----------------
__global__ __launch_bounds__(256, 3) void k_proj(
    const float* __restrict__ act, const float* __restrict__ mask,
    const float* __restrict__ lnw, const float* __restrict__ lnb,
    const u16* __restrict__ wb,
    const float* __restrict__ lpb, const float* __restrict__ lgb,
    const float* __restrict__ rpb, const float* __restrict__ rgb,
    const float* __restrict__ glb,
    u16* __restrict__ left_t, u16* __restrict__ right_t, u16* __restrict__ gate) {
  __shared__ u16 sx[128][128];   // act_ln, XOR-swizzled (key=(row&7)<<3 in u16 units)
  __shared__ u16 stb[128 * 74];  // pair: [128 d][stride 74] wave-private; gate: [64 pos][136]
  __shared__ float fmask[128];
  const int t = threadIdx.x;
  const int pos0 = blockIdx.x * 128;
  const int l = t & 63, w = t >> 6;
  const int lr = l & 15, g4 = l >> 4;

  // ---- phase 1: LayerNorm, 2 threads per row (64 ch each)
  {
    const int r = t >> 1, q = t & 1;
    const float* arow = act + (size_t)(pos0 + r) * CD + q * 64;
    float4 xv[16];
    float s = 0.f, ss = 0.f;
#pragma unroll
    for (int j = 0; j < 16; ++j) {
      xv[j] = *(const float4*)(arow + j * 4);
      s += xv[j].x + xv[j].y + xv[j].z + xv[j].w;
      ss += xv[j].x * xv[j].x + xv[j].y * xv[j].y + xv[j].z * xv[j].z + xv[j].w * xv[j].w;
    }
    s += __shfl_xor(s, 1); ss += __shfl_xor(ss, 1);
    float mu = s * (1.0f / CD);
    float rs = rsqrtf(ss * (1.0f / CD) - mu * mu + 1e-5f);
    const int key = (r & 7) << 3;
#pragma unroll
    for (int j = 0; j < 16; j += 2) {
      u16 o[8] __attribute__((aligned(16)));
      const float* xx = (const float*)&xv[j];
      int c0 = q * 64 + j * 4;
#pragma unroll
      for (int e2 = 0; e2 < 8; ++e2)
        o[e2] = f2bf((xx[e2] - mu) * rs * lnw[c0 + e2] + lnb[c0 + e2]);
      *(bf16x8*)&sx[r][c0 ^ key] = *(const bf16x8*)o;
    }
    if (t < 128) fmask[t] = mask[pos0 + t];
  }
  __syncthreads();

  // ---- pair projection: wave w owns d in [w*32, w*32+32); WAVE-LOCAL staging + dumps
  auto pair_pass = [&](const u16* __restrict__ WP, const u16* __restrict__ WG,
                       const float* __restrict__ bP, const float* __restrict__ bG,
                       u16* __restrict__ dst) {
    bf16x8 bp[2][4], bg[2][4];
    float biasP[2], biasG[2];
    int dd[2];
#pragma unroll
    for (int c2 = 0; c2 < 2; ++c2) {
      dd[c2] = w * 32 + c2 * 16 + lr;
#pragma unroll
      for (int kk = 0; kk < 4; ++kk) {
        bp[c2][kk] = *(const bf16x8*)&WP[dd[c2] * CD + kk * 32 + g4 * 8];
        bg[c2][kk] = *(const bf16x8*)&WG[dd[c2] * CD + kk * 32 + g4 * 8];
      }
      biasP[c2] = bP[dd[c2]];
      biasG[c2] = bG[dd[c2]];
    }
#pragma unroll
    for (int mc = 0; mc < 2; ++mc) {
      lds_fence();   // prior dump-reads retired before this wave overwrites its stb region
#pragma unroll
      for (int m = 0; m < 4; ++m) {
        const int row = mc * 64 + m * 16 + lr;
        const int key = (row & 7) << 3;
        bf16x8 af[4];
#pragma unroll
        for (int kk = 0; kk < 4; ++kk)
          af[kk] = *(const bf16x8*)&sx[row][(kk * 32 + g4 * 8) ^ key];
        const int rowc = m * 16 + g4 * 4;
        float fm[4];
#pragma unroll
        for (int r = 0; r < 4; ++r) fm[r] = fmask[mc * 64 + rowc + r];
#pragma unroll
        for (int c2 = 0; c2 < 2; ++c2) {
          f32x4 aP = {0.f, 0.f, 0.f, 0.f}, aG = {0.f, 0.f, 0.f, 0.f};
#pragma unroll
          for (int kk = 0; kk < 4; ++kk) {
            aP = __builtin_amdgcn_mfma_f32_16x16x32_bf16(af[kk], bp[c2][kk], aP, 0, 0, 0);
            aG = __builtin_amdgcn_mfma_f32_16x16x32_bf16(af[kk], bg[c2][kk], aG, 0, 0, 0);
          }
          u16 o[4] __attribute__((aligned(8)));
#pragma unroll
          for (int r = 0; r < 4; ++r)
            o[r] = f2bf((aP[r] + biasP[c2]) * sigm(aG[r] + biasG[c2]) * fm[r]);
          *(uint2*)&stb[dd[c2] * 74 + rowc] = *(const uint2*)o;
        }
      }
      lds_fence();   // stage-writes complete before this wave's dump-reads
      // wave-local dump: this wave's 32 d x 64 pos; 8 d/instr x 128B contiguous each
#pragma unroll
      for (int it = 0; it < 4; ++it) {
        const int d = w * 32 + it * 8 + (l >> 3), off = (l & 7) * 8;
        *(bf16x8*)&dst[(size_t)d * PS2 + pos0 + mc * 64 + off] = *(const bf16x8*)&stb[d * 74 + off];
      }
    }
  };

  pair_pass(wb, wb + 16384, lpb, lgb, left_t);
  pair_pass(wb + 2 * 16384, wb + 3 * 16384, rpb, rgb, right_t);

  __syncthreads();   // pair stb (wave-private) -> gate stb (cross-wave) region handoff

  // ---- gate: single matrix, pos-major output, staged as [64 pos][stride 136] (cross-wave)
  {
    const u16* WG = wb + 4 * 16384;
    bf16x8 bg[2][4];
    float biasG[2];
    int dd[2];
#pragma unroll
    for (int c2 = 0; c2 < 2; ++c2) {
      dd[c2] = w * 32 + c2 * 16 + lr;
#pragma unroll
      for (int kk = 0; kk < 4; ++kk)
        bg[c2][kk] = *(const bf16x8*)&WG[dd[c2] * CD + kk * 32 + g4 * 8];
      biasG[c2] = glb[dd[c2]];
    }
#pragma unroll
    for (int mc = 0; mc < 2; ++mc) {
#pragma unroll
      for (int m = 0; m < 4; ++m) {
        const int row = mc * 64 + m * 16 + lr;
        const int key = (row & 7) << 3;
        bf16x8 af[4];
#pragma unroll
        for (int kk = 0; kk < 4; ++kk)
          af[kk] = *(const bf16x8*)&sx[row][(kk * 32 + g4 * 8) ^ key];
        const int rowc = m * 16 + g4 * 4;
#pragma unroll
        for (int c2 = 0; c2 < 2; ++c2) {
          f32x4 aG = {0.f, 0.f, 0.f, 0.f};
#pragma unroll
          for (int kk = 0; kk < 4; ++kk)
            aG = __builtin_amdgcn_mfma_f32_16x16x32_bf16(af[kk], bg[c2][kk], aG, 0, 0, 0);
#pragma unroll
          for (int r = 0; r < 4; ++r)
            stb[(rowc + r) * 136 + dd[c2]] = f2bf(sigm(aG[r] + biasG[c2]));   // stride 136 >= 128
        }
      }
      __syncthreads();
      {
        const int row = t >> 2, dc = (t & 3) * 32;
#pragma unroll
        for (int jj = 0; jj < 4; ++jj)
          *(bf16x8*)&gate[(size_t)(pos0 + mc * 64 + row) * CD + dc + jj * 8] =
              *(const bf16x8*)&stb[row * 136 + dc + jj * 8];
      }
      __syncthreads();
    }
  }
}

// ---------------- K2: per-channel triangle GEMM, f32 output, split launch ----------------
__global__ __launch_bounds__(256, 4) void k_tri(
    const u16* __restrict__ left_t, const u16* __restrict__ right_t,
    float* __restrict__ o1, float* __restrict__ o2, float* __restrict__ o3,
    int cbase) {
  __shared__ u16 sA[2][128 * 32];
  __shared__ u16 sB[2][128 * 32];
  const int t = threadIdx.x, l = t & 63, w = t >> 6;
  const int bid = blockIdx.x;                 // 2304 blocks: 64 ch x 36 tiles
  const int xcd = bid & 7, idx = bid >> 3;    // idx in [0,288)
  const int c = cbase + xcd * 8 + idx / 36;
  const int tile = idx - (idx / 36) * 36;
  const int ti = tile / 6, tj = tile - (tile / 6) * 6;
  const u16* A = left_t + (size_t)c * PS2 + (size_t)ti * 128 * NRES;
  const u16* B = right_t + (size_t)c * PS2 + (size_t)tj * 128 * NRES;
  const int lr = l & 15, cj = l >> 4;
  const int wr = (w >> 1) * 64, wc = (w & 1) * 64;
  const int wbase = t & ~63;
  f32x4 acc[4][4];
#pragma unroll
  for (int m = 0; m < 4; ++m)
#pragma unroll
    for (int n = 0; n < 4; ++n) acc[m][n] = (f32x4){0.f, 0.f, 0.f, 0.f};

  // v12 swizzle: LDS slot ch of row holds GLOBAL chunk ch^((row>>1)&3); read slot
  // cj^((row>>1)&3) -> global chunk cj. 8-way bank conflict -> 2-way (free).
  auto stage = [&](int p, int k0) {
#pragma unroll
    for (int it = 0; it < 2; ++it) {
      int li = it * 256 + t;
      int row = li >> 2, ch = li & 3;
      int cs = ch ^ ((row >> 1) & 3);
      async16(&sA[p][(it * 256 + wbase) * 8], A + (size_t)row * NRES + k0 + cs * 8);
      async16(&sB[p][(it * 256 + wbase) * 8], B + (size_t)row * NRES + k0 + cs * 8);
    }
  };

  stage(0, 0);
  __syncthreads();
  for (int ks = 0; ks < 24; ++ks) {
    const int p = ks & 1;
    if (ks < 23) stage(p ^ 1, (ks + 1) * 32);   // prefetch issued BEFORE compute
    bf16x8 av[4], bv[4];
#pragma unroll
    for (int m = 0; m < 4; ++m) {
      const int row = wr + m * 16 + lr;
      av[m] = *(const bf16x8*)&sA[p][row * 32 + ((cj ^ ((row >> 1) & 3)) * 8)];
    }
#pragma unroll
    for (int n = 0; n < 4; ++n) {
      const int row = wc + n * 16 + lr;
      bv[n] = *(const bf16x8*)&sB[p][row * 32 + ((cj ^ ((row >> 1) & 3)) * 8)];
    }
#pragma unroll
    for (int m = 0; m < 4; ++m)
#pragma unroll
      for (int n = 0; n < 4; ++n)
        acc[m][n] = __builtin_amdgcn_mfma_f32_16x16x32_bf16(av[m], bv[n], acc[m][n], 0, 0, 0);
    __syncthreads();   // drains prefetch vmcnt; next iter reads buf p^1
  }

  // f32 output region select (ch 0-63 -> o1; 64-95 -> o2; 96-127 -> o3), skewed planes
  float* O = (c < 64) ? (o1 + (size_t)c * PS4)
           : (c < 96) ? (o2 + (size_t)(c - 64) * PS4)
                      : (o3 + (size_t)(c - 96) * PS4);
  const int r0l = (l >> 4) << 2;
#pragma unroll
  for (int m = 0; m < 4; ++m) {
#pragma unroll
    for (int n = 0; n < 4; ++n) {
      int row = ti * 128 + wr + m * 16 + r0l;
      int col = tj * 128 + wc + n * 16 + lr;
#pragma unroll
      for (int r = 0; r < 4; ++r)
        O[(size_t)(row + r) * NRES + col] = acc[m][n][r];   // 16 lanes x 4B = aligned 64B lines
    }
  }
}

// ---------------- K3: f32 LN + op-linear + gate (256-pos tiles, two-pass) ----------------
__global__ __launch_bounds__(256, 2) void k_post(
    const float* __restrict__ o1, const float* __restrict__ o2, const float* __restrict__ o3,
    const u16* __restrict__ gate,
    const float* __restrict__ clnw, const float* __restrict__ clnb,
    const u16* __restrict__ wop, const float* __restrict__ opb,
    float* __restrict__ out) {
  __shared__ u16 sx[256][128];       // normalized bf16, XOR key (pos&7)<<3 — 64KB
  __shared__ float ps[4][256];       // per-wave partial sums
  __shared__ float pss[4][256];      // per-wave partial sumsq
  __shared__ float mu_s[256], rs_s[256];
  const int t = threadIdx.x;
  const int pos0 = blockIdx.x * 256;
  const int l = t & 63, w = t >> 6;

  // ---- A1: stats. Wave w owns planes [w*32, w*32+32) (region-uniform per wave).
  // Per instruction: 64 lanes x float4 = 1KB CONTIGUOUS from ONE plane (page-friendly).
  {
    const float* wbase = (w < 2) ? (o1 + (size_t)(w * 32) * PS4)
                       : (w == 2) ? o2 : o3;
    float s[4] = {0.f, 0.f, 0.f, 0.f}, ss[4] = {0.f, 0.f, 0.f, 0.f};
#pragma unroll
    for (int pp = 0; pp < 32; ++pp) {
      const float4 v = *(const float4*)&wbase[(size_t)pp * PS4 + pos0 + l * 4];
      s[0] += v.x; ss[0] += v.x * v.x;
      s[1] += v.y; ss[1] += v.y * v.y;
      s[2] += v.z; ss[2] += v.z * v.z;
      s[3] += v.w; ss[3] += v.w * v.w;
    }
#pragma unroll
    for (int e = 0; e < 4; ++e) {
      ps[w][l * 4 + e] = s[e];
      pss[w][l * 4 + e] = ss[e];
    }
  }
  __syncthreads();
  {
    const float s4 = ps[0][t] + ps[1][t] + ps[2][t] + ps[3][t];
    const float ss4 = pss[0][t] + pss[1][t] + pss[2][t] + pss[3][t];
    const float mu = s4 * (1.0f / CD);
    mu_s[t] = mu;
    rs_s[t] = rsqrtf(ss4 * (1.0f / CD) - mu * mu + 1e-5f);
  }
  __syncthreads();

  // ---- A2: re-read (L2-hot), LN once f32->bf16 into sx. v9 thread layout, 4 quarters.
  {
    const int q = t & 15, g = t >> 4;
    const int ch0 = q * 8;
    const float* base = (ch0 < 64) ? (o1 + (size_t)ch0 * PS4)
                      : (ch0 < 96) ? (o2 + (size_t)(ch0 - 64) * PS4)
                                   : (o3 + (size_t)(ch0 - 96) * PS4);
    float4 wv[2], bv[2];
#pragma unroll
    for (int j = 0; j < 2; ++j) {
      wv[j] = *(const float4*)&clnw[ch0 + j * 4];
      bv[j] = *(const float4*)&clnb[ch0 + j * 4];
    }
#pragma unroll
    for (int mc = 0; mc < 4; ++mc) {
      const int p0 = mc * 64 + g * 4;
      float4 x[8];
#pragma unroll
      for (int cc = 0; cc < 8; ++cc)
        x[cc] = *(const float4*)&base[(size_t)cc * PS4 + pos0 + p0];
#pragma unroll
      for (int e = 0; e < 4; ++e) {
        const int p = p0 + e;
        const float mu = mu_s[p], rs = rs_s[p];
        const int key = (p & 7) << 3;
        u16 o8[8] __attribute__((aligned(16)));
#pragma unroll
        for (int i = 0; i < 8; ++i) {
          const float xv = (e == 0) ? x[i].x : (e == 1) ? x[i].y : (e == 2) ? x[i].z : x[i].w;
          const float wvv = ((const float*)&wv[i >> 2])[i & 3];
          const float bvv = ((const float*)&bv[i >> 2])[i & 3];
          o8[i] = f2bf((xv - mu) * rs * wvv + bvv);
        }
        *(bf16x8*)&sx[p][ch0 ^ key] = *(const bf16x8*)o8;
      }
    }
  }
  __syncthreads();

  // ---- C: wave w owns rows [w*64, w*64+64); four 16-row m-tiles (v9 fragment math)
  const int lr = l & 15, lk8 = (l >> 4) * 8;
  bf16x8 af[4][4];
#pragma unroll
  for (int m = 0; m < 4; ++m) {
    const int pr = w * 64 + m * 16 + lr;
    const int key = (pr & 7) << 3;
#pragma unroll
    for (int kk = 0; kk < 4; ++kk)
      af[m][kk] = *(const bf16x8*)&sx[pr][(kk * 32 + lk8) ^ key];
  }
  const int r0l = (l >> 4) << 2;
#pragma unroll
  for (int ct = 0; ct < 8; ++ct) {
    const int d = ct * 16 + lr;
    bf16x8 bv[4];
#pragma unroll
    for (int kk = 0; kk < 4; ++kk)
      bv[kk] = *(const bf16x8*)&wop[d * CD + kk * 32 + lk8];
    const float bo = opb[d];
#pragma unroll
    for (int m = 0; m < 4; ++m) {
      f32x4 acc = {0.f, 0.f, 0.f, 0.f};
#pragma unroll
      for (int kk = 0; kk < 4; ++kk)
        acc = __builtin_amdgcn_mfma_f32_16x16x32_bf16(af[m][kk], bv[kk], acc, 0, 0, 0);
      const int prow = w * 64 + m * 16 + r0l;
#pragma unroll
      for (int r = 0; r < 4; ++r) {
        size_t pp = (size_t)(pos0 + prow + r) * CD + d;
        out[pp] = (acc[r] + bo) * b2f(gate[pp]);
      }
    }
  }
}

extern "C" void kernel_launch(void* const* d_in, const int* in_sizes, int n_in,
                              void* d_out, int out_size, void* d_ws, size_t ws_size,
                              hipStream_t stream) {
  (void)in_sizes; (void)n_in; (void)out_size; (void)ws_size;
  const float* act  = (const float*)d_in[0];
  const float* mask = (const float*)d_in[1];
  const float* lnw  = (const float*)d_in[2];
  const float* lnb  = (const float*)d_in[3];
  const float* lpw  = (const float*)d_in[4];
  const float* lpb  = (const float*)d_in[5];
  const float* rpw  = (const float*)d_in[6];
  const float* rpb  = (const float*)d_in[7];
  const float* lgw  = (const float*)d_in[8];
  const float* lgb  = (const float*)d_in[9];
  const float* rgw  = (const float*)d_in[10];
  const float* rgb  = (const float*)d_in[11];
  const float* clnw = (const float*)d_in[12];
  const float* clnb = (const float*)d_in[13];
  const float* opw  = (const float*)d_in[14];
  const float* opb  = (const float*)d_in[15];
  const float* glw  = (const float*)d_in[16];
  const float* glb  = (const float*)d_in[17];

  char* wsb = (char*)d_ws;
  u16* wb = (u16*)wsb;                            // 6 * 16384 * 2B = 196KB
  const size_t RS = (size_t)128 * PS2 * 2;        // skewed region: 151MB + 32KB
  size_t off = (size_t)1 << 20;
  u16* left_t  = (u16*)(wsb + off); off += RS;
  u16* right_t = (u16*)(wsb + off); off += RS;
  u16* gate    = (u16*)(wsb + off); off += RS;
  float* o1    = (float*)(wsb + off); off += RS;  // f32 ch 0-63: 64*PS4*4 <= RS
  float* o2    = (float*)left_t;                  // f32 ch 64-95 over left_t planes 0-63 (dead)
  float* o3    = (float*)right_t;                 // f32 ch 96-127 over right_t planes 0-63 (dead)

  k_convw<<<384, 256, 0, stream>>>(lpw, lgw, rpw, rgw, glw, opw, wb);
  k_proj<<<NN / 128, 256, 0, stream>>>(act, mask, lnw, lnb, wb,
                                       lpb, lgb, rpb, rgb, glb,
                                       left_t, right_t, gate);
  // launch A: channels 0-63 (reads left/right planes 0-63, writes o1 only)
  k_tri<<<2304, 256, 0, stream>>>(left_t, right_t, o1, o2, o3, 0);
  // launch B: channels 64-127 (reads planes 64-127; writes planes 0-63 regions — dead after A)
  k_tri<<<2304, 256, 0, stream>>>(left_t, right_t, o1, o2, o3, 64);
  k_post<<<NN / 256, 256, 0, stream>>>(o1, o2, o3, gate, clnw, clnb,
                                       wb + 5 * 16384, opb, (float*)d_out);
}